// Round 5
// baseline (190.876 us; speedup 1.0000x reference)
//
#include <hip/hip_runtime.h>

typedef _Float16 half8 __attribute__((ext_vector_type(8)));
typedef _Float16 half4_t __attribute__((ext_vector_type(4)));
typedef float f32x4 __attribute__((ext_vector_type(4)));

#define NBATCH 2048
#define NA 64
#define SA 128
#define HID 256

// LDS (halves): X 8192 (16KB, 16 frags) | R 16384 (32KB, 32 frags) | ATT 8192 (16KB)
// ATT frags 0..7: attnT B-frags; frags 8..15: per-wave q scratch (dbuf).
#define OFF_X 0
#define OFF_R 8192
#define OFF_ATT 24576
#define SMEM_BYTES 65536

// packed fp16 weight offsets (halves) inside d_ws
#define W_ENC1 0
#define W_ENC2 (W_ENC1 + 128 * 256)
#define W_ATTN (W_ENC2 + 256 * 256)
#define W_GC1 (W_ATTN + 256 * 256)
#define W_NN1 (W_GC1 + 128 * 256)
#define W_GC2 (W_NN1 + 128 * 256)
#define W_NN2 (W_GC2 + 256 * 256)

#define MFMA(a, b, cacc) __builtin_amdgcn_mfma_f32_16x16x32_f16((a), (b), (cacc), 0, 0, 0)

// Pack W[K][256] f32 -> B-frag order fp16 (also serves as A-frag of W^T):
// dst[((kt*16+nt)*64+lane)*8 + j] = W[kt*32 + (lane>>4)*8 + j][nt*16 + (lane&15)]
__global__ void pack_all(const float* __restrict__ e1, const float* __restrict__ e2,
                         const float* __restrict__ aw, const float* __restrict__ g1,
                         const float* __restrict__ n1, const float* __restrict__ g2,
                         const float* __restrict__ n2, _Float16* __restrict__ dst) {
  int b = (int)blockIdx.x;
  const float* src;
  int off;
  if (b < 16) { src = e1; off = W_ENC1; }
  else if (b < 48) { src = e2; off = W_ENC2; b -= 16; }
  else if (b < 80) { src = aw; off = W_ATTN; b -= 48; }
  else if (b < 96) { src = g1; off = W_GC1; b -= 80; }
  else if (b < 112) { src = n1; off = W_NN1; b -= 96; }
  else if (b < 144) { src = g2; off = W_GC2; b -= 112; }
  else { src = n2; off = W_NN2; b -= 144; }
  int t = b * 256 + (int)threadIdx.x;
  int lane = t & 63, frag = t >> 6;
  int nt = frag & 15, kt = frag >> 4;
  int g = lane >> 4, c = lane & 15;
  half8 h;
#pragma unroll
  for (int j = 0; j < 8; ++j)
    h[j] = (_Float16)src[(size_t)(kt * 32 + g * 8 + j) * 256 + nt * 16 + c];
  *(half8*)(dst + off + (size_t)t * 8) = h;
}

__global__ __launch_bounds__(256, 2) void dicg_main(
    const float* __restrict__ x, const float* __restrict__ b_enc1,
    const float* __restrict__ b_enc2, const float* __restrict__ b_gc1,
    const float* __restrict__ b_nn1, const float* __restrict__ b_gc2,
    const float* __restrict__ b_nn2, const _Float16* __restrict__ wp,
    float* __restrict__ out, float* __restrict__ attn_out) {
  extern __shared__ _Float16 sm[];
  _Float16* X = sm + OFF_X;    // x frags (kt*4+nt)
  _Float16* R = sm + OFF_R;    // h1T -> embT -> xg1T(TS) -> featT -> fg2T(TS)
  _Float16* AT = sm + OFF_ATT; // attnT frags + q scratch

  const int tid = (int)threadIdx.x;
  const int wv = tid >> 6;  // wave: owns hid-rows (transposed) / hid-cols (normal) 64*wv..+63
  const int lane = tid & 63;
  const int g = lane >> 4;  // 0..3
  const int c = lane & 15;  // 0..15
  const int bb = (int)blockIdx.x;
  const float* __restrict__ xb = x + (size_t)bb * (NA * SA);

  // fragment-linear b128 read (conflict-free)
  auto ldF = [&](const _Float16* p, int fi) -> half8 {
    return *(const half8*)(p + fi * 512 + lane * 8);
  };
  auto wfrag = [&](const _Float16* wb, int kt, int ntg) -> half8 {
    return *(const half8*)(wb + ((size_t)(kt * 16 + ntg) * 64 + lane) * 8);
  };
  auto xfrag = [&](int r0, int k0) -> half8 {
    const float* p = xb + (r0 + c) * SA + k0 + g * 8;
    f32x4 u = *(const f32x4*)p;
    f32x4 v = *(const f32x4*)(p + 4);
    half8 h;
    h[0] = (_Float16)u[0]; h[1] = (_Float16)u[1];
    h[2] = (_Float16)u[2]; h[3] = (_Float16)u[3];
    h[4] = (_Float16)v[0]; h[5] = (_Float16)v[1];
    h[6] = (_Float16)v[2]; h[7] = (_Float16)v[3];
    return h;
  };

  // FS store: transposed-GEMM D tile (mt,nt): value rows k0=64wv+16mt+4g+r, cols 16nt+c.
  // -> B-frag-linear: fi=(k0>>5)*4+nt, lane_t=16*((k0>>3)&3)+c, j=k0&7=4(g&1)+r  (half4)
  auto stFS = [&](_Float16* p, int mt, int nt, half4_t hv) {
    int fi = (2 * wv + (mt >> 1)) * 4 + nt;
    int gt = (2 * mt + (g >> 1)) & 3;
    *(half4_t*)(p + fi * 512 + (16 * gt + c) * 8 + 4 * (g & 1)) = hv;
  };
  // TS store: normal-GEMM D tile (rt,nt): rows a0=16rt+4g+r, cols h=64wv+16nt+c.
  // -> A-frag-of-M^T: fi=(a0>>5)*16 + (h>>4), lane_t=16*((a0>>3)&3)+c, j=a0&7 (half4)
  auto stTS = [&](_Float16* p, int rt, int nt, half4_t hv) {
    int fi = (rt >> 1) * 16 + 4 * wv + nt;
    int gt = (2 * rt + (g >> 1)) & 3;
    *(half4_t*)(p + fi * 512 + (16 * gt + c) * 8 + 4 * (g & 1)) = hv;
  };
  // q scratch: tiles Mt=2s+t -> B-frag slot (per-wave dbuf)
  auto stQ = [&](const f32x4(&qa)[2], int slot) {
    _Float16* base = AT + (8 + 2 * wv + slot) * 512;
#pragma unroll
    for (int t = 0; t < 2; ++t) {
      half4_t hv;
#pragma unroll
      for (int r = 0; r < 4; ++r) hv[r] = (_Float16)qa[t][r];
      int gt = (2 * t + (g >> 1)) & 3;
      *(half4_t*)(base + (16 * gt + c) * 8 + 4 * (g & 1)) = hv;
    }
  };

  // ===== P1: h1T = W1T·xT (+bias row, relu) -> R ; stage x frags -> X =====
  {
    f32x4 acc[4][4]{};
#pragma unroll
    for (int kt = 0; kt < 4; ++kt) {
      half8 xf[4];
#pragma unroll
      for (int nt = 0; nt < 4; ++nt) xf[nt] = xfrag(16 * nt, kt * 32);
      if (kt == wv) {
#pragma unroll
        for (int nt = 0; nt < 4; ++nt)
          *(half8*)(X + (kt * 4 + nt) * 512 + lane * 8) = xf[nt];
      }
#pragma unroll
      for (int mt = 0; mt < 4; ++mt) {
        half8 wf = wfrag(wp + W_ENC1, kt, 4 * wv + mt);
#pragma unroll
        for (int nt = 0; nt < 4; ++nt) acc[mt][nt] = MFMA(wf, xf[nt], acc[mt][nt]);
      }
    }
#pragma unroll
    for (int mt = 0; mt < 4; ++mt) {
      f32x4 bv = *(const f32x4*)(b_enc1 + 64 * wv + 16 * mt + 4 * g);
#pragma unroll
      for (int nt = 0; nt < 4; ++nt) {
        half4_t hv;
#pragma unroll
        for (int r = 0; r < 4; ++r) hv[r] = (_Float16)fmaxf(acc[mt][nt][r] + bv[r], 0.f);
        stFS(R, mt, nt, hv);
      }
    }
  }
  __syncthreads();  // B1
  // ===== P2: embT = W2T·h1T (+bias, relu), in-place over R =====
  {
    f32x4 acc[4][4]{};
#pragma unroll
    for (int kt = 0; kt < 8; ++kt) {
      half8 bf[4];
#pragma unroll
      for (int nt = 0; nt < 4; ++nt) bf[nt] = ldF(R, kt * 4 + nt);
#pragma unroll
      for (int mt = 0; mt < 4; ++mt) {
        half8 wf = wfrag(wp + W_ENC2, kt, 4 * wv + mt);
#pragma unroll
        for (int nt = 0; nt < 4; ++nt) acc[mt][nt] = MFMA(wf, bf[nt], acc[mt][nt]);
      }
    }
    __syncthreads();  // B2: all h1T reads done
#pragma unroll
    for (int mt = 0; mt < 4; ++mt) {
      f32x4 bv = *(const f32x4*)(b_enc2 + 64 * wv + 16 * mt + 4 * g);
#pragma unroll
      for (int nt = 0; nt < 4; ++nt) {
        half4_t hv;
#pragma unroll
        for (int r = 0; r < 4; ++r) hv[r] = (_Float16)fmaxf(acc[mt][nt][r] + bv[r], 0.f);
        stFS(R, mt, nt, hv);
      }
    }
  }
  __syncthreads();  // B3
  // ===== P3+P4: qT tiles (pipelined via scratch) -> ST = emb·qT, softmax =====
  {
    half8 ebK[8];
#pragma unroll
    for (int kt = 0; kt < 8; ++kt) ebK[kt] = ldF(R, kt * 4 + wv);
    f32x4 sc[4]{};
    auto qtile = [&](int s, f32x4(&qa)[2]) {
#pragma unroll
      for (int kt = 0; kt < 8; ++kt) {
        qa[0] = MFMA(wfrag(wp + W_ATTN, kt, 2 * s), ebK[kt], qa[0]);
        qa[1] = MFMA(wfrag(wp + W_ATTN, kt, 2 * s + 1), ebK[kt], qa[1]);
      }
    };
    {
      f32x4 qa[2]{};
      qtile(0, qa);
      stQ(qa, 0);
    }
#pragma unroll
    for (int s = 0; s < 8; ++s) {
      f32x4 qn[2]{};
      if (s < 7) qtile(s + 1, qn);
      asm volatile("s_waitcnt lgkmcnt(0)" ::: "memory");
      half8 qb = *(const half8*)(AT + (8 + 2 * wv + (s & 1)) * 512 + lane * 8);
      if (s < 7) stQ(qn, (s + 1) & 1);
#pragma unroll
      for (int mt = 0; mt < 4; ++mt) sc[mt] = MFMA(ldF(R, s * 4 + mt), qb, sc[mt]);
    }
    // softmax over m for query n=16wv+c (16 vals/thread, partners lanes xor 16/32)
    float m0 = sc[0][0];
#pragma unroll
    for (int mt = 0; mt < 4; ++mt)
#pragma unroll
      for (int r = 0; r < 4; ++r) m0 = fmaxf(m0, sc[mt][r]);
    m0 = fmaxf(m0, __shfl_xor(m0, 16));
    m0 = fmaxf(m0, __shfl_xor(m0, 32));
    float e[4][4], ssum = 0.f;
#pragma unroll
    for (int mt = 0; mt < 4; ++mt)
#pragma unroll
      for (int r = 0; r < 4; ++r) {
        e[mt][r] = __expf(sc[mt][r] - m0);
        ssum += e[mt][r];
      }
    ssum += __shfl_xor(ssum, 16);
    ssum += __shfl_xor(ssum, 32);
    float inv = 1.0f / ssum;
    float* ao = attn_out + ((size_t)bb * NA + 16 * wv + c) * NA;
#pragma unroll
    for (int mt = 0; mt < 4; ++mt) {
      f32x4 vv;
      half4_t hv;
#pragma unroll
      for (int r = 0; r < 4; ++r) {
        vv[r] = e[mt][r] * inv;
        hv[r] = (_Float16)vv[r];
      }
      *(f32x4*)(ao + 16 * mt + 4 * g) = vv;
      int fi = (mt >> 1) * 4 + wv;  // attnT B-frag: rows m, col-group wv
      int gt = (2 * mt + (g >> 1)) & 3;
      *(half4_t*)(AT + fi * 512 + (16 * gt + c) * 8 + 4 * (g & 1)) = hv;
    }
  }
  __syncthreads();  // B4: embT reads done; attnT complete
  // ===== P5 fused over x: xg1 = x·G1 (+bias, TS->R) ; nn1T = relu(N1T·xT+b) regs =====
  half4_t r1h[4][4];
  {
    f32x4 aG[4][4]{}, aN[4][4]{};
#pragma unroll
    for (int kt = 0; kt < 4; ++kt) {
      half8 xf[4];
#pragma unroll
      for (int i = 0; i < 4; ++i) xf[i] = ldF(X, kt * 4 + i);
#pragma unroll
      for (int nt = 0; nt < 4; ++nt) {
        half8 g1f = wfrag(wp + W_GC1, kt, 4 * wv + nt);
#pragma unroll
        for (int rt = 0; rt < 4; ++rt) aG[rt][nt] = MFMA(xf[rt], g1f, aG[rt][nt]);
      }
#pragma unroll
      for (int mt = 0; mt < 4; ++mt) {
        half8 n1f = wfrag(wp + W_NN1, kt, 4 * wv + mt);
#pragma unroll
        for (int nt = 0; nt < 4; ++nt) aN[mt][nt] = MFMA(n1f, xf[nt], aN[mt][nt]);
      }
    }
#pragma unroll
    for (int nt = 0; nt < 4; ++nt) {
      float bv = b_gc1[64 * wv + 16 * nt + c];
#pragma unroll
      for (int rt = 0; rt < 4; ++rt) {
        half4_t hv;
#pragma unroll
        for (int r = 0; r < 4; ++r) hv[r] = (_Float16)(aG[rt][nt][r] + bv);
        stTS(R, rt, nt, hv);
      }
    }
#pragma unroll
    for (int mt = 0; mt < 4; ++mt) {
      f32x4 bv = *(const f32x4*)(b_nn1 + 64 * wv + 16 * mt + 4 * g);
#pragma unroll
      for (int nt = 0; nt < 4; ++nt)
#pragma unroll
        for (int r = 0; r < 4; ++r)
          r1h[mt][nt][r] = (_Float16)fmaxf(aN[mt][nt][r] + bv[r], 0.f);
    }
  }
  __syncthreads();  // B5
  // ===== P6: featT = (relu(xg1T·attnT) + nn1T)/64 -> R (in-place) =====
  {
    f32x4 a1[4][4]{};
#pragma unroll
    for (int kt = 0; kt < 2; ++kt) {
      half8 atf[4];
#pragma unroll
      for (int nt = 0; nt < 4; ++nt) atf[nt] = ldF(AT, kt * 4 + nt);
#pragma unroll
      for (int mt = 0; mt < 4; ++mt) {
        half8 xgf = ldF(R, kt * 16 + 4 * wv + mt);
#pragma unroll
        for (int nt = 0; nt < 4; ++nt) a1[mt][nt] = MFMA(xgf, atf[nt], a1[mt][nt]);
      }
    }
    __syncthreads();  // B6: all xg1 reads done
#pragma unroll
    for (int mt = 0; mt < 4; ++mt)
#pragma unroll
      for (int nt = 0; nt < 4; ++nt) {
        half4_t hv;
#pragma unroll
        for (int r = 0; r < 4; ++r)
          hv[r] = (_Float16)((fmaxf(a1[mt][nt][r], 0.f) + (float)r1h[mt][nt][r]) * 0.015625f);
        stFS(R, mt, nt, hv);
      }
  }
  __syncthreads();  // B7: featT complete
  // ===== P7 fused over feat: nn2T = relu(N2T·featT+b) regs ; fg2 = feat·G2 (+b, TS) =====
  half4_t r2h[4][4];
  {
    f32x4 aN2[4][4]{}, aG2[4][4]{};
#pragma unroll
    for (int kt = 0; kt < 8; ++kt) {
      half8 ff[4];
#pragma unroll
      for (int i = 0; i < 4; ++i) ff[i] = ldF(R, kt * 4 + i);
#pragma unroll
      for (int mt = 0; mt < 4; ++mt) {
        half8 n2f = wfrag(wp + W_NN2, kt, 4 * wv + mt);
#pragma unroll
        for (int nt = 0; nt < 4; ++nt) aN2[mt][nt] = MFMA(n2f, ff[nt], aN2[mt][nt]);
      }
#pragma unroll
      for (int nt = 0; nt < 4; ++nt) {
        half8 g2f = wfrag(wp + W_GC2, kt, 4 * wv + nt);
#pragma unroll
        for (int rt = 0; rt < 4; ++rt) aG2[rt][nt] = MFMA(ff[rt], g2f, aG2[rt][nt]);
      }
    }
#pragma unroll
    for (int mt = 0; mt < 4; ++mt) {
      f32x4 bv = *(const f32x4*)(b_nn2 + 64 * wv + 16 * mt + 4 * g);
#pragma unroll
      for (int nt = 0; nt < 4; ++nt)
#pragma unroll
        for (int r = 0; r < 4; ++r)
          r2h[mt][nt][r] = (_Float16)fmaxf(aN2[mt][nt][r] + bv[r], 0.f);
    }
    __syncthreads();  // B8: all featT reads done
#pragma unroll
    for (int nt = 0; nt < 4; ++nt) {
      float bv = b_gc2[64 * wv + 16 * nt + c];
#pragma unroll
      for (int rt = 0; rt < 4; ++rt) {
        half4_t hv;
#pragma unroll
        for (int r = 0; r < 4; ++r) hv[r] = (_Float16)(aG2[rt][nt][r] + bv);
        stTS(R, rt, nt, hv);
      }
    }
  }
  __syncthreads();  // B9
  // ===== P8: outT = (relu(fg2T·attnT) + nn2T)/64 -> global =====
  {
    f32x4 a1[4][4]{};
#pragma unroll
    for (int kt = 0; kt < 2; ++kt) {
      half8 atf[4];
#pragma unroll
      for (int nt = 0; nt < 4; ++nt) atf[nt] = ldF(AT, kt * 4 + nt);
#pragma unroll
      for (int mt = 0; mt < 4; ++mt) {
        half8 fgf = ldF(R, kt * 16 + 4 * wv + mt);
#pragma unroll
        for (int nt = 0; nt < 4; ++nt) a1[mt][nt] = MFMA(fgf, atf[nt], a1[mt][nt]);
      }
    }
    float* ob = out + (size_t)bb * NA * HID;
#pragma unroll
    for (int mt = 0; mt < 4; ++mt)
#pragma unroll
      for (int nt = 0; nt < 4; ++nt) {
        f32x4 vv;
#pragma unroll
        for (int r = 0; r < 4; ++r)
          vv[r] = (fmaxf(a1[mt][nt][r], 0.f) + (float)r2h[mt][nt][r]) * 0.015625f;
        *(f32x4*)(ob + (size_t)(16 * nt + c) * HID + 64 * wv + 16 * mt + 4 * g) = vv;
      }
  }
}

extern "C" void kernel_launch(void* const* d_in, const int* in_sizes, int n_in,
                              void* d_out, int out_size, void* d_ws, size_t ws_size,
                              hipStream_t stream) {
  const float* x = (const float*)d_in[0];
  const float* enc_w1 = (const float*)d_in[1];
  const float* enc_b1 = (const float*)d_in[2];
  const float* enc_w2 = (const float*)d_in[3];
  const float* enc_b2 = (const float*)d_in[4];
  const float* attn_w = (const float*)d_in[5];
  const float* gc1_w = (const float*)d_in[6];
  const float* gc1_b = (const float*)d_in[7];
  const float* nn1_w = (const float*)d_in[8];
  const float* nn1_b = (const float*)d_in[9];
  const float* gc2_w = (const float*)d_in[10];
  const float* gc2_b = (const float*)d_in[11];
  const float* nn2_w = (const float*)d_in[12];
  const float* nn2_b = (const float*)d_in[13];
  // d_in[14] = n_agents (=64, compile-time constant)

  _Float16* wp = (_Float16*)d_ws;
  float* out = (float*)d_out;
  float* attn_o = out + (size_t)NBATCH * NA * HID;

  pack_all<<<176, 256, 0, stream>>>(enc_w1, enc_w2, attn_w, gc1_w, nn1_w, gc2_w,
                                    nn2_w, wp);
  dicg_main<<<NBATCH, 256, SMEM_BYTES, stream>>>(
      x, enc_b1, enc_b2, gc1_b, nn1_b, gc2_b, nn2_b, wp, out, attn_o);
}